// Round 1
// baseline (1296.761 us; speedup 1.0000x reference)
//
#include <hip/hip_runtime.h>
#include <hip/hip_bf16.h>

#define B_ 4
#define S_ 1024
#define E_ 1024
#define H_ 16
#define D_ 64
#define NEGV (-1e9f)

// ---------------- mask symmetrize: msym = mask | mask^T (uint8) ----------------
__global__ __launch_bounds__(256) void mask_sym_kernel(const int* __restrict__ mask,
                                                       unsigned char* __restrict__ msym) {
  const int blk = blockIdx.x;            // B * 32 * 32 = 4096
  const int b = blk >> 10;
  const int rest = blk & 1023;
  const int i0 = (rest >> 5) << 5;
  const int j0 = (rest & 31) << 5;
  __shared__ int T[32][33];
  const int tid = threadIdx.x;
  const int ii = tid >> 3;               // 0..31
  const int jj4 = (tid & 7) << 2;        // 0..28
  const size_t bO = (size_t)b * S_ * S_;
  // T[a][c] = mask[b][j0+a][i0+c]
  const int4 m2 = *(const int4*)&mask[bO + (size_t)(j0 + ii) * S_ + i0 + jj4];
  T[ii][jj4 + 0] = m2.x; T[ii][jj4 + 1] = m2.y; T[ii][jj4 + 2] = m2.z; T[ii][jj4 + 3] = m2.w;
  __syncthreads();
  const int4 m1 = *(const int4*)&mask[bO + (size_t)(i0 + ii) * S_ + j0 + jj4];
  uchar4 o;
  o.x = ((m1.x != 0) || (T[jj4 + 0][ii] != 0)) ? 1 : 0;
  o.y = ((m1.y != 0) || (T[jj4 + 1][ii] != 0)) ? 1 : 0;
  o.z = ((m1.z != 0) || (T[jj4 + 2][ii] != 0)) ? 1 : 0;
  o.w = ((m1.w != 0) || (T[jj4 + 3][ii] != 0)) ? 1 : 0;
  *(uchar4*)&msym[bO + (size_t)(i0 + ii) * S_ + j0 + jj4] = o;
}

// ---------------- fp32 GEMM: C[4096x1024] = A[4096x1024] @ W[1024x1024] ----------------
__global__ __launch_bounds__(256) void gemm64_kernel(const float* __restrict__ A,
                                                     const float* __restrict__ W,
                                                     float* __restrict__ C) {
  __shared__ __align__(16) float As[32][68];  // As[k][m], +4 pad: conflict-free, 16B-aligned rows
  __shared__ __align__(16) float Bs[32][68];  // Bs[k][n]
  const int tid = threadIdx.x;
  const int m0 = (blockIdx.x & 63) << 6;
  const int n0 = (blockIdx.x >> 6) << 6;
  const int tx = tid & 15, ty = tid >> 4;
  float acc[4][4] = {};
  for (int k0 = 0; k0 < E_; k0 += 32) {
    // A tile 64x32 -> As transposed
#pragma unroll
    for (int t = 0; t < 2; ++t) {
      const int f = tid + t * 256;
      const int r = f >> 3, c4 = (f & 7) << 2;
      const float4 av = *(const float4*)&A[(size_t)(m0 + r) * E_ + k0 + c4];
      As[c4 + 0][r] = av.x; As[c4 + 1][r] = av.y; As[c4 + 2][r] = av.z; As[c4 + 3][r] = av.w;
    }
    // B tile 32x64
#pragma unroll
    for (int t = 0; t < 2; ++t) {
      const int f = tid + t * 256;
      const int r = f >> 4, c4 = (f & 15) << 2;
      *(float4*)&Bs[r][c4] = *(const float4*)&W[(size_t)(k0 + r) * E_ + n0 + c4];
    }
    __syncthreads();
#pragma unroll
    for (int kk = 0; kk < 32; ++kk) {
      const float4 a = *(const float4*)&As[kk][ty << 2];
      const float4 b = *(const float4*)&Bs[kk][tx << 2];
      const float av[4] = {a.x, a.y, a.z, a.w};
      const float bv[4] = {b.x, b.y, b.z, b.w};
#pragma unroll
      for (int i = 0; i < 4; ++i)
#pragma unroll
        for (int j = 0; j < 4; ++j) acc[i][j] += av[i] * bv[j];
    }
    __syncthreads();
  }
#pragma unroll
  for (int i = 0; i < 4; ++i) {
    const float4 o = {acc[i][0], acc[i][1], acc[i][2], acc[i][3]};
    *(float4*)&C[(size_t)(m0 + (ty << 2) + i) * E_ + n0 + (tx << 2)] = o;
  }
}

// ---------------- bias + LayerNorm + ReLU, in place, one row per block ----------------
__global__ __launch_bounds__(256) void ln_relu_kernel(float* __restrict__ P,
                                                      const float* __restrict__ bias,
                                                      const float* __restrict__ gamma,
                                                      const float* __restrict__ beta) {
  float* p = P + (size_t)blockIdx.x * E_;
  const int tid = threadIdx.x;
  float4 v = ((const float4*)p)[tid];
  const float4 bb = ((const float4*)bias)[tid];
  v.x += bb.x; v.y += bb.y; v.z += bb.z; v.w += bb.w;
  float s = v.x + v.y + v.z + v.w;
  float s2 = v.x * v.x + v.y * v.y + v.z * v.z + v.w * v.w;
#pragma unroll
  for (int off = 32; off >= 1; off >>= 1) {
    s += __shfl_xor(s, off);
    s2 += __shfl_xor(s2, off);
  }
  __shared__ float red[2][4];
  const int wave = tid >> 6, lane = tid & 63;
  if (lane == 0) { red[0][wave] = s; red[1][wave] = s2; }
  __syncthreads();
  s = red[0][0] + red[0][1] + red[0][2] + red[0][3];
  s2 = red[1][0] + red[1][1] + red[1][2] + red[1][3];
  const float mu = s * (1.0f / E_);
  const float var = s2 * (1.0f / E_) - mu * mu;
  const float r = rsqrtf(var + 1e-5f);
  const float4 g = ((const float4*)gamma)[tid];
  const float4 bt = ((const float4*)beta)[tid];
  v.x = fmaxf((v.x - mu) * r * g.x + bt.x, 0.0f);
  v.y = fmaxf((v.y - mu) * r * g.y + bt.y, 0.0f);
  v.z = fmaxf((v.z - mu) * r * g.z + bt.z, 0.0f);
  v.w = fmaxf((v.w - mu) * r * g.w + bt.w, 0.0f);
  ((float4*)p)[tid] = v;
}

// ---------------- scores + mask + softmax + head-mean ----------------
// block: (b, 8 q-rows). waves: (qg in {0,1}) x (head-half in {0,1}).
// per lane: 16 keys (k = j*64+lane), scores s[4q][16k] in regs, K streamed from global.
__global__ __launch_bounds__(256, 2) void attn_kernel(const float* __restrict__ Qb,
                                                      const float* __restrict__ Kb,
                                                      const unsigned char* __restrict__ msym,
                                                      float* __restrict__ out) {
  __shared__ __align__(16) float Qs[8 * E_];      // 32KB
  __shared__ __align__(16) float outAcc[8 * S_];  // 32KB
  const int tid = threadIdx.x;
  const int wave = tid >> 6, lane = tid & 63;
  const int blk = blockIdx.x;         // 512
  const int b = blk & 3;              // XCD%4 -> one K[b] per XCD's L2
  const int q0 = (blk >> 2) << 3;
  {
    const float4* src = (const float4*)(Qb + (size_t)(b * S_ + q0) * E_);
    float4* dq = (float4*)Qs;
    float4* doa = (float4*)outAcc;
    const float4 z = {0.0f, 0.0f, 0.0f, 0.0f};
#pragma unroll
    for (int i = 0; i < 8; ++i) {
      dq[tid + i * 256] = src[tid + i * 256];
      doa[tid + i * 256] = z;
    }
  }
  __syncthreads();
  const int qg = wave & 1;
  const int hh = wave >> 1;
  const float4* Qs4 = (const float4*)Qs;
  for (int hi = 0; hi < 8; ++hi) {
    const int h = hh * 8 + hi;
    float s[4][16];
#pragma unroll
    for (int jg = 0; jg < 4; ++jg) {
      const float4* kp0 = (const float4*)(Kb + (size_t)(b * S_ + (jg * 4 + 0) * 64 + lane) * E_ + h * D_);
      const float4* kp1 = (const float4*)(Kb + (size_t)(b * S_ + (jg * 4 + 1) * 64 + lane) * E_ + h * D_);
      const float4* kp2 = (const float4*)(Kb + (size_t)(b * S_ + (jg * 4 + 2) * 64 + lane) * E_ + h * D_);
      const float4* kp3 = (const float4*)(Kb + (size_t)(b * S_ + (jg * 4 + 3) * 64 + lane) * E_ + h * D_);
      float acc[4][4] = {};
#pragma unroll
      for (int d4 = 0; d4 < 16; ++d4) {
        const float4 k0 = kp0[d4];
        const float4 k1 = kp1[d4];
        const float4 k2 = kp2[d4];
        const float4 k3 = kp3[d4];
#pragma unroll
        for (int q = 0; q < 4; ++q) {
          const float4 qv = Qs4[(qg * 4 + q) * 256 + h * 16 + d4];  // wave-uniform -> LDS broadcast
          acc[q][0] += qv.x * k0.x + qv.y * k0.y + qv.z * k0.z + qv.w * k0.w;
          acc[q][1] += qv.x * k1.x + qv.y * k1.y + qv.z * k1.z + qv.w * k1.w;
          acc[q][2] += qv.x * k2.x + qv.y * k2.y + qv.z * k2.z + qv.w * k2.w;
          acc[q][3] += qv.x * k3.x + qv.y * k3.y + qv.z * k3.z + qv.w * k3.w;
        }
      }
#pragma unroll
      for (int q = 0; q < 4; ++q)
#pragma unroll
        for (int c = 0; c < 4; ++c) s[q][jg * 4 + c] = acc[q][c] * 0.125f;
    }
    // symmetric mask
#pragma unroll
    for (int q = 0; q < 4; ++q) {
      const unsigned char* mrow = msym + (size_t)(b * S_ + q0 + qg * 4 + q) * S_ + lane;
#pragma unroll
      for (int j = 0; j < 16; ++j)
        if (mrow[j * 64]) s[q][j] = NEGV;
    }
    // softmax over keys (exact, handles all-masked row == uniform like jax)
#pragma unroll
    for (int q = 0; q < 4; ++q) {
      float m = s[q][0];
#pragma unroll
      for (int j = 1; j < 16; ++j) m = fmaxf(m, s[q][j]);
#pragma unroll
      for (int off = 32; off >= 1; off >>= 1) m = fmaxf(m, __shfl_xor(m, off));
      float l = 0.0f;
#pragma unroll
      for (int j = 0; j < 16; ++j) {
        const float e = __expf(s[q][j] - m);
        s[q][j] = e;
        l += e;
      }
#pragma unroll
      for (int off = 32; off >= 1; off >>= 1) l += __shfl_xor(l, off);
      const float sc = 1.0f / (l * (float)H_);
#pragma unroll
      for (int j = 0; j < 16; ++j)
        atomicAdd(&outAcc[(qg * 4 + q) * S_ + j * 64 + lane], s[q][j] * sc);
    }
  }
  __syncthreads();
  {
    float4* dst = (float4*)(out + (size_t)(b * S_ + q0) * S_);
    const float4* srcO = (const float4*)outAcc;
#pragma unroll
    for (int i = 0; i < 8; ++i) dst[tid + i * 256] = srcO[tid + i * 256];
  }
}

extern "C" void kernel_launch(void* const* d_in, const int* in_sizes, int n_in,
                              void* d_out, int out_size, void* d_ws, size_t ws_size,
                              hipStream_t stream) {
  const float* x = (const float*)d_in[0];
  const int* mask = (const int*)d_in[1];
  const float* Wq = (const float*)d_in[2];
  const float* bq = (const float*)d_in[3];
  const float* Wk = (const float*)d_in[4];
  const float* bk = (const float*)d_in[5];
  const float* gq = (const float*)d_in[6];
  const float* bq_n = (const float*)d_in[7];
  const float* gk = (const float*)d_in[8];
  const float* bk_n = (const float*)d_in[9];
  float* out = (float*)d_out;

  char* ws = (char*)d_ws;
  float* Pq = (float*)ws;                                    // 16 MB
  float* Pk = (float*)(ws + (size_t)16 * 1024 * 1024);       // 16 MB
  unsigned char* msym = (unsigned char*)(ws + (size_t)32 * 1024 * 1024);  // 4 MB

  mask_sym_kernel<<<4096, 256, 0, stream>>>(mask, msym);
  gemm64_kernel<<<1024, 256, 0, stream>>>(x, Wq, Pq);
  gemm64_kernel<<<1024, 256, 0, stream>>>(x, Wk, Pk);
  ln_relu_kernel<<<4096, 256, 0, stream>>>(Pq, bq, gq, bq_n);
  ln_relu_kernel<<<4096, 256, 0, stream>>>(Pk, bk, gk, bk_n);
  attn_kernel<<<512, 256, 0, stream>>>(Pq, Pk, msym, out);
}

// Round 2
// 738.695 us; speedup vs baseline: 1.7555x; 1.7555x over previous
//
#include <hip/hip_runtime.h>
#include <hip/hip_bf16.h>

#define B_ 4
#define S_ 1024
#define E_ 1024
#define H_ 16
#define D_ 64

typedef __attribute__((ext_vector_type(8))) short short8;
typedef __attribute__((ext_vector_type(4))) float f32x4;

static __device__ __forceinline__ unsigned short f2bf(float x) {
  unsigned int u = __float_as_uint(x);
  unsigned int r = u + 0x7fffu + ((u >> 16) & 1u);  // round-to-nearest-even
  return (unsigned short)(r >> 16);
}

// ---------------- mask symmetrize: msym = mask | mask^T (uint8) ----------------
__global__ __launch_bounds__(256) void mask_sym_kernel(const int* __restrict__ mask,
                                                       unsigned char* __restrict__ msym) {
  const int blk = blockIdx.x;            // B * 32 * 32 = 4096
  const int b = blk >> 10;
  const int rest = blk & 1023;
  const int i0 = (rest >> 5) << 5;
  const int j0 = (rest & 31) << 5;
  __shared__ int T[32][33];
  const int tid = threadIdx.x;
  const int ii = tid >> 3;               // 0..31
  const int jj4 = (tid & 7) << 2;        // 0..28
  const size_t bO = (size_t)b * S_ * S_;
  const int4 m2 = *(const int4*)&mask[bO + (size_t)(j0 + ii) * S_ + i0 + jj4];
  T[ii][jj4 + 0] = m2.x; T[ii][jj4 + 1] = m2.y; T[ii][jj4 + 2] = m2.z; T[ii][jj4 + 3] = m2.w;
  __syncthreads();
  const int4 m1 = *(const int4*)&mask[bO + (size_t)(i0 + ii) * S_ + j0 + jj4];
  uchar4 o;
  o.x = ((m1.x != 0) || (T[jj4 + 0][ii] != 0)) ? 1 : 0;
  o.y = ((m1.y != 0) || (T[jj4 + 1][ii] != 0)) ? 1 : 0;
  o.z = ((m1.z != 0) || (T[jj4 + 2][ii] != 0)) ? 1 : 0;
  o.w = ((m1.w != 0) || (T[jj4 + 3][ii] != 0)) ? 1 : 0;
  *(uchar4*)&msym[bO + (size_t)(i0 + ii) * S_ + j0 + jj4] = o;
}

// ---------------- fp32 GEMM: C[4096x1024] = A[4096x1024] @ W[1024x1024] ----------------
__global__ __launch_bounds__(256) void gemm64_kernel(const float* __restrict__ A,
                                                     const float* __restrict__ W,
                                                     float* __restrict__ C) {
  __shared__ __align__(16) float As[32][68];
  __shared__ __align__(16) float Bs[32][68];
  const int tid = threadIdx.x;
  const int m0 = (blockIdx.x & 63) << 6;
  const int n0 = (blockIdx.x >> 6) << 6;
  const int tx = tid & 15, ty = tid >> 4;
  float acc[4][4] = {};
  for (int k0 = 0; k0 < E_; k0 += 32) {
#pragma unroll
    for (int t = 0; t < 2; ++t) {
      const int f = tid + t * 256;
      const int r = f >> 3, c4 = (f & 7) << 2;
      const float4 av = *(const float4*)&A[(size_t)(m0 + r) * E_ + k0 + c4];
      As[c4 + 0][r] = av.x; As[c4 + 1][r] = av.y; As[c4 + 2][r] = av.z; As[c4 + 3][r] = av.w;
    }
#pragma unroll
    for (int t = 0; t < 2; ++t) {
      const int f = tid + t * 256;
      const int r = f >> 4, c4 = (f & 15) << 2;
      *(float4*)&Bs[r][c4] = *(const float4*)&W[(size_t)(k0 + r) * E_ + n0 + c4];
    }
    __syncthreads();
#pragma unroll
    for (int kk = 0; kk < 32; ++kk) {
      const float4 a = *(const float4*)&As[kk][ty << 2];
      const float4 b = *(const float4*)&Bs[kk][tx << 2];
      const float av[4] = {a.x, a.y, a.z, a.w};
      const float bv[4] = {b.x, b.y, b.z, b.w};
#pragma unroll
      for (int i = 0; i < 4; ++i)
#pragma unroll
        for (int j = 0; j < 4; ++j) acc[i][j] += av[i] * bv[j];
    }
    __syncthreads();
  }
#pragma unroll
  for (int i = 0; i < 4; ++i) {
    const float4 o = {acc[i][0], acc[i][1], acc[i][2], acc[i][3]};
    *(float4*)&C[(size_t)(m0 + (ty << 2) + i) * E_ + n0 + (tx << 2)] = o;
  }
}

// ------- bias + LayerNorm + ReLU; emit bf16 head-major [b*16+h][s][d] -------
__global__ __launch_bounds__(256) void ln_relu_bf_kernel(const float* __restrict__ P,
                                                         const float* __restrict__ bias,
                                                         const float* __restrict__ gamma,
                                                         const float* __restrict__ beta,
                                                         unsigned short* __restrict__ obf) {
  const int row = blockIdx.x;            // b*1024 + s
  const int b = row >> 10, s = row & 1023;
  const float* p = P + (size_t)row * E_;
  const int tid = threadIdx.x;
  float4 v = ((const float4*)p)[tid];
  const float4 bb = ((const float4*)bias)[tid];
  v.x += bb.x; v.y += bb.y; v.z += bb.z; v.w += bb.w;
  float sum = v.x + v.y + v.z + v.w;
  float s2 = v.x * v.x + v.y * v.y + v.z * v.z + v.w * v.w;
#pragma unroll
  for (int off = 32; off >= 1; off >>= 1) {
    sum += __shfl_xor(sum, off);
    s2 += __shfl_xor(s2, off);
  }
  __shared__ float red[2][4];
  const int wave = tid >> 6, lane = tid & 63;
  if (lane == 0) { red[0][wave] = sum; red[1][wave] = s2; }
  __syncthreads();
  sum = red[0][0] + red[0][1] + red[0][2] + red[0][3];
  s2 = red[1][0] + red[1][1] + red[1][2] + red[1][3];
  const float mu = sum * (1.0f / E_);
  const float var = s2 * (1.0f / E_) - mu * mu;
  const float r = rsqrtf(var + 1e-5f);
  const float4 g = ((const float4*)gamma)[tid];
  const float4 bt = ((const float4*)beta)[tid];
  float o0 = fmaxf((v.x - mu) * r * g.x + bt.x, 0.0f);
  float o1 = fmaxf((v.y - mu) * r * g.y + bt.y, 0.0f);
  float o2 = fmaxf((v.z - mu) * r * g.z + bt.z, 0.0f);
  float o3 = fmaxf((v.w - mu) * r * g.w + bt.w, 0.0f);
  const int h = tid >> 4;                // (tid*4)/64
  const int d = (tid & 15) << 2;
  ushort4 ob = {f2bf(o0), f2bf(o1), f2bf(o2), f2bf(o3)};
  *(ushort4*)&obf[((size_t)(b * H_ + h) * S_ + s) * D_ + d] = ob;
}

// ---------------- fused scores + mask + softmax + head-mean (MFMA) ----------------
// block: (b, 16-q tile). 8 waves x 2 heads. MFMA 16x16x32 bf16, K-dim = 64 = 2 steps.
// C-layout (m89): col(key) = lane&15, row(q) = (lane>>4)*4 + reg.
__global__ __launch_bounds__(512, 2) void attn2_kernel(const unsigned short* __restrict__ Qbf,
                                                       const unsigned short* __restrict__ Kbf,
                                                       const unsigned char* __restrict__ msym,
                                                       float* __restrict__ out) {
  __shared__ __align__(16) float outAcc[16 * 1028];  // 64.25 KB; +4 pad -> 2-way (free) conflicts
  unsigned char* smask = (unsigned char*)outAcc;     // aliased: mask phase precedes acc phase
  const int tid = threadIdx.x;
  const int wave = tid >> 6, lane = tid & 63;
  const int ln15 = lane & 15, rg = lane >> 4;        // rg = row-group 0..3
  const int blk = blockIdx.x;
  const int b = blk & 3;                             // XCD%4 -> one K[b] per XCD's L2
  const int q0 = (blk >> 2) << 4;

  // phase 1: stage msym rows [16][1024] bytes into LDS
  {
    const int row = tid >> 5, c0 = (tid & 31) << 5;
    const uint4* src = (const uint4*)(msym + ((size_t)b * S_ + q0 + row) * S_ + c0);
    const uint4 m0 = src[0], m1 = src[1];
    *(uint4*)&smask[row * 1024 + c0] = m0;
    *(uint4*)&smask[row * 1024 + c0 + 16] = m1;
  }
  __syncthreads();
  // per-lane bitmasks: mrow[r] bit kt = msym[q0 + rg*4 + r][kt*16 + ln15]
  unsigned long long mrow[4] = {0ull, 0ull, 0ull, 0ull};
#pragma unroll
  for (int kt = 0; kt < 64; ++kt) {
#pragma unroll
    for (int r = 0; r < 4; ++r)
      mrow[r] |= (unsigned long long)(smask[(rg * 4 + r) * 1024 + kt * 16 + ln15] ? 1u : 0u) << kt;
  }
  __syncthreads();
  // phase 2: zero outAcc
  for (int i = tid; i < 16 * 1028; i += 512) outAcc[i] = 0.0f;
  __syncthreads();

  // phase 3: per wave, 2 heads
  for (int hi = 0; hi < 2; ++hi) {
    const int h = wave * 2 + hi;
    const size_t hbase = (size_t)(b * H_ + h) * S_ * D_;
    // A-frags: Q[q0+ln15][d = rg*8 + j (+32)]
    const short8 a0 = *(const short8*)(Qbf + hbase + (size_t)(q0 + ln15) * D_ + rg * 8);
    const short8 a1 = *(const short8*)(Qbf + hbase + (size_t)(q0 + ln15) * D_ + rg * 8 + 32);
    const size_t kbase = hbase + (size_t)ln15 * D_ + rg * 8;
    unsigned int epack[64][2];
    float l[4] = {0.0f, 0.0f, 0.0f, 0.0f};
#pragma unroll
    for (int kt = 0; kt < 64; ++kt) {
      const unsigned short* kp = Kbf + kbase + (size_t)kt * (16 * D_);
      const short8 b0 = *(const short8*)(kp);
      const short8 b1 = *(const short8*)(kp + 32);
      f32x4 c = {0.0f, 0.0f, 0.0f, 0.0f};
      c = __builtin_amdgcn_mfma_f32_16x16x32_bf16(a0, b0, c, 0, 0, 0);
      c = __builtin_amdgcn_mfma_f32_16x16x32_bf16(a1, b1, c, 0, 0, 0);
      float e[4];
#pragma unroll
      for (int r = 0; r < 4; ++r) {
        const float s = fminf(c[r] * 0.125f, 80.0f);   // overflow guard; s >= 0 normally
        const float ev = ((mrow[r] >> kt) & 1ull) ? 0.0f : __expf(s);
        e[r] = ev;
        l[r] += ev;
      }
      epack[kt][0] = (unsigned)f2bf(e[0]) | ((unsigned)f2bf(e[1]) << 16);
      epack[kt][1] = (unsigned)f2bf(e[2]) | ((unsigned)f2bf(e[3]) << 16);
    }
    // reduce l over the 16 lanes sharing each q-row (lane&15 = key dimension)
#pragma unroll
    for (int r = 0; r < 4; ++r) {
      float lv = l[r];
      lv += __shfl_xor(lv, 1);
      lv += __shfl_xor(lv, 2);
      lv += __shfl_xor(lv, 4);
      lv += __shfl_xor(lv, 8);
      l[r] = 0.0625f / lv;  // 1/(l*16): head-mean folded in
    }
    // scaled accumulation into shared outAcc
#pragma unroll
    for (int kt = 0; kt < 64; ++kt) {
      const unsigned u0 = epack[kt][0], u1 = epack[kt][1];
      const float e0 = __uint_as_float(u0 << 16);
      const float e1 = __uint_as_float(u0 & 0xFFFF0000u);
      const float e2 = __uint_as_float(u1 << 16);
      const float e3 = __uint_as_float(u1 & 0xFFFF0000u);
      float* oa = &outAcc[kt * 16 + ln15];
      atomicAdd(oa + (rg * 4 + 0) * 1028, e0 * l[0]);
      atomicAdd(oa + (rg * 4 + 1) * 1028, e1 * l[1]);
      atomicAdd(oa + (rg * 4 + 2) * 1028, e2 * l[2]);
      atomicAdd(oa + (rg * 4 + 3) * 1028, e3 * l[3]);
    }
  }
  __syncthreads();
  // phase 4: write out [16 rows x 1024]
  {
    const int row = tid >> 5, c0 = (tid & 31) << 5;
    float* dst = out + ((size_t)b * S_ + q0 + row) * S_ + c0;
    const float* srcA = &outAcc[row * 1028 + c0];
#pragma unroll
    for (int i = 0; i < 8; ++i)
      *(float4*)(dst + i * 4) = *(const float4*)(srcA + i * 4);
  }
}

extern "C" void kernel_launch(void* const* d_in, const int* in_sizes, int n_in,
                              void* d_out, int out_size, void* d_ws, size_t ws_size,
                              hipStream_t stream) {
  const float* x = (const float*)d_in[0];
  const int* mask = (const int*)d_in[1];
  const float* Wq = (const float*)d_in[2];
  const float* bq = (const float*)d_in[3];
  const float* Wk = (const float*)d_in[4];
  const float* bk = (const float*)d_in[5];
  const float* gq = (const float*)d_in[6];
  const float* bq_n = (const float*)d_in[7];
  const float* gk = (const float*)d_in[8];
  const float* bk_n = (const float*)d_in[9];
  float* out = (float*)d_out;

  char* ws = (char*)d_ws;
  float* P = (float*)ws;                                             // 16 MB (reused Q then K)
  unsigned short* Qbf = (unsigned short*)(ws + (size_t)16 * 1024 * 1024);  // 8 MB
  unsigned short* Kbf = (unsigned short*)(ws + (size_t)24 * 1024 * 1024);  // 8 MB
  unsigned char* msym = (unsigned char*)(ws + (size_t)32 * 1024 * 1024);   // 4 MB

  mask_sym_kernel<<<4096, 256, 0, stream>>>(mask, msym);
  gemm64_kernel<<<1024, 256, 0, stream>>>(x, Wq, P);
  ln_relu_bf_kernel<<<4096, 256, 0, stream>>>(P, bq, gq, bq_n, Qbf);
  gemm64_kernel<<<1024, 256, 0, stream>>>(x, Wk, P);
  ln_relu_bf_kernel<<<4096, 256, 0, stream>>>(P, bk, gk, bk_n, Kbf);
  attn2_kernel<<<256, 512, 0, stream>>>(Qbf, Kbf, msym, out);
}

// Round 3
// 474.660 us; speedup vs baseline: 2.7320x; 1.5563x over previous
//
#include <hip/hip_runtime.h>
#include <hip/hip_bf16.h>

#define B_ 4
#define S_ 1024
#define E_ 1024
#define H_ 16
#define D_ 64

typedef __attribute__((ext_vector_type(8))) short short8;
typedef __attribute__((ext_vector_type(4))) float f32x4;

static __device__ __forceinline__ unsigned short f2bf(float x) {
  unsigned int u = __float_as_uint(x);
  unsigned int r = u + 0x7fffu + ((u >> 16) & 1u);  // round-to-nearest-even
  return (unsigned short)(r >> 16);
}

// ---------------- mask symmetrize: msym = mask | mask^T (uint8) ----------------
__global__ __launch_bounds__(256) void mask_sym_kernel(const int* __restrict__ mask,
                                                       unsigned char* __restrict__ msym) {
  const int blk = blockIdx.x;            // B * 32 * 32 = 4096
  const int b = blk >> 10;
  const int rest = blk & 1023;
  const int i0 = (rest >> 5) << 5;
  const int j0 = (rest & 31) << 5;
  __shared__ int T[32][33];
  const int tid = threadIdx.x;
  const int ii = tid >> 3;               // 0..31
  const int jj4 = (tid & 7) << 2;        // 0..28
  const size_t bO = (size_t)b * S_ * S_;
  const int4 m2 = *(const int4*)&mask[bO + (size_t)(j0 + ii) * S_ + i0 + jj4];
  T[ii][jj4 + 0] = m2.x; T[ii][jj4 + 1] = m2.y; T[ii][jj4 + 2] = m2.z; T[ii][jj4 + 3] = m2.w;
  __syncthreads();
  const int4 m1 = *(const int4*)&mask[bO + (size_t)(i0 + ii) * S_ + j0 + jj4];
  uchar4 o;
  o.x = ((m1.x != 0) || (T[jj4 + 0][ii] != 0)) ? 1 : 0;
  o.y = ((m1.y != 0) || (T[jj4 + 1][ii] != 0)) ? 1 : 0;
  o.z = ((m1.z != 0) || (T[jj4 + 2][ii] != 0)) ? 1 : 0;
  o.w = ((m1.w != 0) || (T[jj4 + 3][ii] != 0)) ? 1 : 0;
  *(uchar4*)&msym[bO + (size_t)(i0 + ii) * S_ + j0 + jj4] = o;
}

// ---------------- fp32 GEMM: C[4096x1024] = A[4096x1024] @ W[1024x1024] ----------------
__global__ __launch_bounds__(256) void gemm64_kernel(const float* __restrict__ A,
                                                     const float* __restrict__ W,
                                                     float* __restrict__ C) {
  __shared__ __align__(16) float As[32][68];
  __shared__ __align__(16) float Bs[32][68];
  const int tid = threadIdx.x;
  const int m0 = (blockIdx.x & 63) << 6;
  const int n0 = (blockIdx.x >> 6) << 6;
  const int tx = tid & 15, ty = tid >> 4;
  float acc[4][4] = {};
  for (int k0 = 0; k0 < E_; k0 += 32) {
#pragma unroll
    for (int t = 0; t < 2; ++t) {
      const int f = tid + t * 256;
      const int r = f >> 3, c4 = (f & 7) << 2;
      const float4 av = *(const float4*)&A[(size_t)(m0 + r) * E_ + k0 + c4];
      As[c4 + 0][r] = av.x; As[c4 + 1][r] = av.y; As[c4 + 2][r] = av.z; As[c4 + 3][r] = av.w;
    }
#pragma unroll
    for (int t = 0; t < 2; ++t) {
      const int f = tid + t * 256;
      const int r = f >> 4, c4 = (f & 15) << 2;
      *(float4*)&Bs[r][c4] = *(const float4*)&W[(size_t)(k0 + r) * E_ + n0 + c4];
    }
    __syncthreads();
#pragma unroll
    for (int kk = 0; kk < 32; ++kk) {
      const float4 a = *(const float4*)&As[kk][ty << 2];
      const float4 b = *(const float4*)&Bs[kk][tx << 2];
      const float av[4] = {a.x, a.y, a.z, a.w};
      const float bv[4] = {b.x, b.y, b.z, b.w};
#pragma unroll
      for (int i = 0; i < 4; ++i)
#pragma unroll
        for (int j = 0; j < 4; ++j) acc[i][j] += av[i] * bv[j];
    }
    __syncthreads();
  }
#pragma unroll
  for (int i = 0; i < 4; ++i) {
    const float4 o = {acc[i][0], acc[i][1], acc[i][2], acc[i][3]};
    *(float4*)&C[(size_t)(m0 + (ty << 2) + i) * E_ + n0 + (tx << 2)] = o;
  }
}

// ------- bias + LayerNorm + ReLU; emit bf16 head-major [b*16+h][s][d] -------
__global__ __launch_bounds__(256) void ln_relu_bf_kernel(const float* __restrict__ P,
                                                         const float* __restrict__ bias,
                                                         const float* __restrict__ gamma,
                                                         const float* __restrict__ beta,
                                                         unsigned short* __restrict__ obf) {
  const int row = blockIdx.x;            // b*1024 + s
  const int b = row >> 10, s = row & 1023;
  const float* p = P + (size_t)row * E_;
  const int tid = threadIdx.x;
  float4 v = ((const float4*)p)[tid];
  const float4 bb = ((const float4*)bias)[tid];
  v.x += bb.x; v.y += bb.y; v.z += bb.z; v.w += bb.w;
  float sum = v.x + v.y + v.z + v.w;
  float s2 = v.x * v.x + v.y * v.y + v.z * v.z + v.w * v.w;
#pragma unroll
  for (int off = 32; off >= 1; off >>= 1) {
    sum += __shfl_xor(sum, off);
    s2 += __shfl_xor(s2, off);
  }
  __shared__ float red[2][4];
  const int wave = tid >> 6, lane = tid & 63;
  if (lane == 0) { red[0][wave] = sum; red[1][wave] = s2; }
  __syncthreads();
  sum = red[0][0] + red[0][1] + red[0][2] + red[0][3];
  s2 = red[1][0] + red[1][1] + red[1][2] + red[1][3];
  const float mu = sum * (1.0f / E_);
  const float var = s2 * (1.0f / E_) - mu * mu;
  const float r = rsqrtf(var + 1e-5f);
  const float4 g = ((const float4*)gamma)[tid];
  const float4 bt = ((const float4*)beta)[tid];
  float o0 = fmaxf((v.x - mu) * r * g.x + bt.x, 0.0f);
  float o1 = fmaxf((v.y - mu) * r * g.y + bt.y, 0.0f);
  float o2 = fmaxf((v.z - mu) * r * g.z + bt.z, 0.0f);
  float o3 = fmaxf((v.w - mu) * r * g.w + bt.w, 0.0f);
  const int h = tid >> 4;                // (tid*4)/64
  const int d = (tid & 15) << 2;
  ushort4 ob = {f2bf(o0), f2bf(o1), f2bf(o2), f2bf(o3)};
  *(ushort4*)&obf[((size_t)(b * H_ + h) * S_ + s) * D_ + d] = ob;
}

// ---------------- fused scores + mask + softmax + head-mean (MFMA, no atomics) ------
// block: (b, 16-q tile), 512 thr = 8 waves. Waves own disjoint 128-key slices; loop
// over all 16 heads. Pass A: partial softmax denominators l per head (LDS cross-wave
// reduce). Pass B: recompute exp, weight by 1/(16*l), sum over heads in registers ->
// each (q,row, key,col) cell owned by exactly one lane -> plain stores, zero atomics.
// MFMA 16x16x32 bf16; C-layout: col(key)=lane&15, row(q)=(lane>>4)*4+reg.
__global__ __launch_bounds__(512, 2) void attn3_kernel(const unsigned short* __restrict__ Qbf,
                                                       const unsigned short* __restrict__ Kbf,
                                                       const unsigned char* __restrict__ msym,
                                                       float* __restrict__ out) {
  __shared__ __align__(16) float outAcc[16 * 1028];   // 64.25 KB; +4 pad -> 2-way (free)
  __shared__ __align__(16) float l_lds[8 * 16 * 16];  // [wave][h][q] 8 KB
  __shared__ __align__(16) float linv_lds[16 * 16];   // [h][q] 1 KB
  unsigned char* smask = (unsigned char*)outAcc;      // aliased: mask phase precedes stores
  const int tid = threadIdx.x;
  const int wave = tid >> 6, lane = tid & 63;
  const int ln15 = lane & 15, rg = lane >> 4;
  const int blk = blockIdx.x;
  const int b = blk & 3;                              // XCD swizzle: one (Q,K)[b] per XCD L2
  const int q0 = (blk >> 2) << 4;

  // stage msym rows [16][1024] into LDS
  {
    const int row = tid >> 5, c0 = (tid & 31) << 5;
    const uint4* src = (const uint4*)(msym + ((size_t)b * S_ + q0 + row) * S_ + c0);
    const uint4 m0 = src[0], m1 = src[1];
    *(uint4*)&smask[row * 1024 + c0] = m0;
    *(uint4*)&smask[row * 1024 + c0 + 16] = m1;
  }
  __syncthreads();
  // per-lane mask bits for this wave's 8 key-tiles: bit j = msym[rg*4+r][(wave*8+j)*16+ln15]
  unsigned int mrow[4] = {0u, 0u, 0u, 0u};
#pragma unroll
  for (int j = 0; j < 8; ++j) {
    const int col = (wave * 8 + j) * 16 + ln15;
#pragma unroll
    for (int r = 0; r < 4; ++r)
      mrow[r] |= (smask[(rg * 4 + r) * 1024 + col] ? 1u : 0u) << j;
  }

  const size_t bbase = (size_t)b * H_ * S_ * D_;
  const size_t qoff = (size_t)(q0 + ln15) * D_ + rg * 8;
  const size_t koff = (size_t)(wave * 128 + ln15) * D_ + rg * 8;

  // ---- pass A: per-head partial denominators over this wave's 128 keys ----
#pragma unroll 1
  for (int h = 0; h < 16; ++h) {
    const size_t hbase = bbase + (size_t)h * S_ * D_;
    const unsigned short* qp = Qbf + hbase + qoff;
    const short8 a0 = *(const short8*)qp;
    const short8 a1 = *(const short8*)(qp + 32);
    const unsigned short* kp = Kbf + hbase + koff;
    float la[4] = {0.0f, 0.0f, 0.0f, 0.0f};
#pragma unroll
    for (int j = 0; j < 8; ++j) {
      const unsigned short* kpj = kp + (size_t)j * (16 * D_);
      const short8 b0 = *(const short8*)kpj;
      const short8 b1 = *(const short8*)(kpj + 32);
      f32x4 c = {0.0f, 0.0f, 0.0f, 0.0f};
      c = __builtin_amdgcn_mfma_f32_16x16x32_bf16(a0, b0, c, 0, 0, 0);
      c = __builtin_amdgcn_mfma_f32_16x16x32_bf16(a1, b1, c, 0, 0, 0);
#pragma unroll
      for (int r = 0; r < 4; ++r) {
        const float s = fminf(c[r] * 0.125f, 80.0f);
        la[r] += ((mrow[r] >> j) & 1u) ? 0.0f : __expf(s);
      }
    }
    // reduce over the 16 key-lanes sharing each q-row
#pragma unroll
    for (int r = 0; r < 4; ++r) {
      float lv = la[r];
      lv += __shfl_xor(lv, 1);
      lv += __shfl_xor(lv, 2);
      lv += __shfl_xor(lv, 4);
      lv += __shfl_xor(lv, 8);
      la[r] = lv;
    }
    if (ln15 == 0) {
      const float4 lw = {la[0], la[1], la[2], la[3]};
      *(float4*)&l_lds[(wave * 16 + h) * 16 + rg * 4] = lw;
    }
  }
  __syncthreads();
  // cross-wave reduce: linv[h][q] = 1 / (16 * sum_w l[w][h][q])
  if (tid < 256) {
    const int h = tid >> 4, q = tid & 15;
    float s = 0.0f;
#pragma unroll
    for (int w = 0; w < 8; ++w) s += l_lds[(w * 16 + h) * 16 + q];
    linv_lds[h * 16 + q] = 0.0625f / s;
  }
  __syncthreads();

  // ---- pass B: recompute exp, weight, sum over heads in registers ----
  float o[8][4] = {};
#pragma unroll 1
  for (int h = 0; h < 16; ++h) {
    const size_t hbase = bbase + (size_t)h * S_ * D_;
    const unsigned short* qp = Qbf + hbase + qoff;
    const short8 a0 = *(const short8*)qp;
    const short8 a1 = *(const short8*)(qp + 32);
    const float4 li4 = *(const float4*)&linv_lds[h * 16 + rg * 4];
    const float li[4] = {li4.x, li4.y, li4.z, li4.w};
    const unsigned short* kp = Kbf + hbase + koff;
#pragma unroll
    for (int j = 0; j < 8; ++j) {
      const unsigned short* kpj = kp + (size_t)j * (16 * D_);
      const short8 b0 = *(const short8*)kpj;
      const short8 b1 = *(const short8*)(kpj + 32);
      f32x4 c = {0.0f, 0.0f, 0.0f, 0.0f};
      c = __builtin_amdgcn_mfma_f32_16x16x32_bf16(a0, b0, c, 0, 0, 0);
      c = __builtin_amdgcn_mfma_f32_16x16x32_bf16(a1, b1, c, 0, 0, 0);
#pragma unroll
      for (int r = 0; r < 4; ++r) {
        const float s = fminf(c[r] * 0.125f, 80.0f);
        const float e = ((mrow[r] >> j) & 1u) ? 0.0f : __expf(s);
        o[j][r] += e * li[r];
      }
    }
  }
  // each cell (rg*4+r, wave*8+j, ln15) owned by exactly this lane: plain stores
#pragma unroll
  for (int j = 0; j < 8; ++j)
#pragma unroll
    for (int r = 0; r < 4; ++r)
      outAcc[(rg * 4 + r) * 1028 + (wave * 8 + j) * 16 + ln15] = o[j][r];
  __syncthreads();
  // coalesced write-out [16 rows x 1024]
  {
    const int row = tid >> 5, c0 = (tid & 31) << 5;
    float* dst = out + ((size_t)b * S_ + q0 + row) * S_ + c0;
    const float* srcA = &outAcc[row * 1028 + c0];
#pragma unroll
    for (int i = 0; i < 8; ++i)
      *(float4*)(dst + i * 4) = *(const float4*)(srcA + i * 4);
  }
}

extern "C" void kernel_launch(void* const* d_in, const int* in_sizes, int n_in,
                              void* d_out, int out_size, void* d_ws, size_t ws_size,
                              hipStream_t stream) {
  const float* x = (const float*)d_in[0];
  const int* mask = (const int*)d_in[1];
  const float* Wq = (const float*)d_in[2];
  const float* bq = (const float*)d_in[3];
  const float* Wk = (const float*)d_in[4];
  const float* bk = (const float*)d_in[5];
  const float* gq = (const float*)d_in[6];
  const float* bq_n = (const float*)d_in[7];
  const float* gk = (const float*)d_in[8];
  const float* bk_n = (const float*)d_in[9];
  float* out = (float*)d_out;

  char* ws = (char*)d_ws;
  float* P = (float*)ws;                                                   // 16 MB (Q then K)
  unsigned short* Qbf = (unsigned short*)(ws + (size_t)16 * 1024 * 1024);  // 8 MB
  unsigned short* Kbf = (unsigned short*)(ws + (size_t)24 * 1024 * 1024);  // 8 MB
  unsigned char* msym = (unsigned char*)(ws + (size_t)32 * 1024 * 1024);   // 4 MB

  mask_sym_kernel<<<4096, 256, 0, stream>>>(mask, msym);
  gemm64_kernel<<<1024, 256, 0, stream>>>(x, Wq, P);
  ln_relu_bf_kernel<<<4096, 256, 0, stream>>>(P, bq, gq, bq_n, Qbf);
  gemm64_kernel<<<1024, 256, 0, stream>>>(x, Wk, P);
  ln_relu_bf_kernel<<<4096, 256, 0, stream>>>(P, bk, gk, bk_n, Kbf);
  attn3_kernel<<<256, 512, 0, stream>>>(Qbf, Kbf, msym, out);
}

// Round 4
// 279.283 us; speedup vs baseline: 4.6432x; 1.6996x over previous
//
#include <hip/hip_runtime.h>
#include <hip/hip_bf16.h>

#define B_ 4
#define S_ 1024
#define E_ 1024
#define H_ 16
#define D_ 64

typedef __attribute__((ext_vector_type(8))) short short8;
typedef __attribute__((ext_vector_type(4))) float f32x4;

static __device__ __forceinline__ unsigned short f2bf(float x) {
  unsigned int u = __float_as_uint(x);
  unsigned int r = u + 0x7fffu + ((u >> 16) & 1u);  // round-to-nearest-even
  return (unsigned short)(r >> 16);
}
static __device__ __forceinline__ float bf2f(unsigned short b) {
  return __uint_as_float((unsigned int)b << 16);
}

#define GL2LDS16(g, l)                                                            \
  __builtin_amdgcn_global_load_lds(                                               \
      (const __attribute__((address_space(1))) unsigned int*)(g),                 \
      (__attribute__((address_space(3))) unsigned int*)(l), 16, 0, 0)

// ---------------- mask symmetrize: msym = mask | mask^T (uint8) ----------------
__global__ __launch_bounds__(256) void mask_sym_kernel(const int* __restrict__ mask,
                                                       unsigned char* __restrict__ msym) {
  const int blk = blockIdx.x;            // B * 32 * 32 = 4096
  const int b = blk >> 10;
  const int rest = blk & 1023;
  const int i0 = (rest >> 5) << 5;
  const int j0 = (rest & 31) << 5;
  __shared__ int T[32][33];
  const int tid = threadIdx.x;
  const int ii = tid >> 3;
  const int jj4 = (tid & 7) << 2;
  const size_t bO = (size_t)b * S_ * S_;
  const int4 m2 = *(const int4*)&mask[bO + (size_t)(j0 + ii) * S_ + i0 + jj4];
  T[ii][jj4 + 0] = m2.x; T[ii][jj4 + 1] = m2.y; T[ii][jj4 + 2] = m2.z; T[ii][jj4 + 3] = m2.w;
  __syncthreads();
  const int4 m1 = *(const int4*)&mask[bO + (size_t)(i0 + ii) * S_ + j0 + jj4];
  uchar4 o;
  o.x = ((m1.x != 0) || (T[jj4 + 0][ii] != 0)) ? 1 : 0;
  o.y = ((m1.y != 0) || (T[jj4 + 1][ii] != 0)) ? 1 : 0;
  o.z = ((m1.z != 0) || (T[jj4 + 2][ii] != 0)) ? 1 : 0;
  o.w = ((m1.w != 0) || (T[jj4 + 3][ii] != 0)) ? 1 : 0;
  *(uchar4*)&msym[bO + (size_t)(i0 + ii) * S_ + j0 + jj4] = o;
}

// ---------------- x fp32 -> bf16 ----------------
__global__ __launch_bounds__(256) void cvt_x_kernel(const float* __restrict__ x,
                                                    unsigned short* __restrict__ o) {
  const size_t i = ((size_t)blockIdx.x * 256 + threadIdx.x) * 8;
  const float4 a = *(const float4*)(x + i);
  const float4 b = *(const float4*)(x + i + 4);
  const ushort4 p0 = {f2bf(a.x), f2bf(a.y), f2bf(a.z), f2bf(a.w)};
  const ushort4 p1 = {f2bf(b.x), f2bf(b.y), f2bf(b.z), f2bf(b.w)};
  *(ushort4*)(o + i) = p0;
  *(ushort4*)(o + i + 4) = p1;
}

// -------- W fp32 [k][n] -> Wt bf16 [n][k], both mats stacked: Wt[2048][1024] --------
__global__ __launch_bounds__(256) void wt_kernel(const float* __restrict__ Wq,
                                                 const float* __restrict__ Wk,
                                                 unsigned short* __restrict__ Wt) {
  const int blk = blockIdx.x;            // 2 * 32 * 32
  const int mat = blk >> 10;
  const int kt = (blk >> 5) & 31, ntb = blk & 31;
  const float* W = mat ? Wk : Wq;
  __shared__ unsigned short T[32][36];   // T[k][n], padded
  const int tid = threadIdx.x;
  const int r = tid >> 3, c4 = (tid & 7) << 2;
  const float4 v = *(const float4*)&W[(size_t)(kt * 32 + r) * 1024 + ntb * 32 + c4];
  T[r][c4 + 0] = f2bf(v.x); T[r][c4 + 1] = f2bf(v.y);
  T[r][c4 + 2] = f2bf(v.z); T[r][c4 + 3] = f2bf(v.w);
  __syncthreads();
  const ushort4 o = {T[c4 + 0][r], T[c4 + 1][r], T[c4 + 2][r], T[c4 + 3][r]};
  *(ushort4*)&Wt[(size_t)(mat * 1024 + ntb * 32 + r) * 1024 + kt * 32 + c4] = o;
}

// ------- bf16 MFMA GEMM: P[4096][nstride] = xbf[4096][1024] @ Wt^T (Wt is [n][k]) -----
// 128x128 tile, BK=32, 4 waves (2x2), 4x4 16x16x32 frags/wave, global_load_lds staging.
__global__ __launch_bounds__(256) void gemm_mfma_kernel(const unsigned short* __restrict__ Abf,
                                                        const unsigned short* __restrict__ Wt,
                                                        unsigned short* __restrict__ P,
                                                        int nstride) {
  __shared__ __align__(16) unsigned short As[128 * 32];  // 8 KB, [m][k]
  __shared__ __align__(16) unsigned short Bs[128 * 32];  // 8 KB, [n][k]
  const int tid = threadIdx.x;
  const int m0 = (blockIdx.x & 31) << 7;
  const int n0 = (blockIdx.x >> 5) << 7;
  const int wave = tid >> 6, lane = tid & 63;
  const int ln15 = lane & 15, rg = lane >> 4;
  const int wm = (wave & 1) << 6;
  const int wn = (wave >> 1) << 6;
  // staging: thread covers 16B of row (sr) col (sc); chunk2 = rows +64
  const int sr = tid >> 2;
  const int sc = (tid & 3) << 3;
  const unsigned short* gA = Abf + (size_t)(m0 + sr) * 1024 + sc;
  const unsigned short* gB = Wt + (size_t)(n0 + sr) * 1024 + sc;
  unsigned short* lA = As + tid * 8;
  unsigned short* lB = Bs + tid * 8;
  f32x4 acc[4][4];
#pragma unroll
  for (int i = 0; i < 4; ++i)
#pragma unroll
    for (int j = 0; j < 4; ++j) acc[i][j] = (f32x4){0.0f, 0.0f, 0.0f, 0.0f};

  const unsigned short* pa = As + (wm + ln15) * 32 + rg * 8;
  const unsigned short* pb = Bs + (wn + ln15) * 32 + rg * 8;
  for (int k0 = 0; k0 < E_; k0 += 32) {
    GL2LDS16(gA + k0, lA);
    GL2LDS16(gA + k0 + (size_t)64 * 1024, lA + 2048);
    GL2LDS16(gB + k0, lB);
    GL2LDS16(gB + k0 + (size_t)64 * 1024, lB + 2048);
    __syncthreads();
    short8 af[4], bfr[4];
#pragma unroll
    for (int i = 0; i < 4; ++i) af[i] = *(const short8*)(pa + i * 16 * 32);
#pragma unroll
    for (int j = 0; j < 4; ++j) bfr[j] = *(const short8*)(pb + j * 16 * 32);
#pragma unroll
    for (int i = 0; i < 4; ++i)
#pragma unroll
      for (int j = 0; j < 4; ++j)
        acc[i][j] = __builtin_amdgcn_mfma_f32_16x16x32_bf16(af[i], bfr[j], acc[i][j], 0, 0, 0);
    __syncthreads();
  }
  // epilogue: C-layout col=lane&15, row=rg*4+reg
#pragma unroll
  for (int i = 0; i < 4; ++i)
#pragma unroll
    for (int j = 0; j < 4; ++j)
#pragma unroll
      for (int r = 0; r < 4; ++r) {
        const int row = m0 + wm + i * 16 + rg * 4 + r;
        const int col = n0 + wn + j * 16 + ln15;
        P[(size_t)row * nstride + col] = f2bf(acc[i][j][r]);
      }
}

// ------- bias + LayerNorm + ReLU from bf16 P; emit bf16 head-major [b*16+h][s][d] -------
__global__ __launch_bounds__(256) void ln_relu_bf_kernel(const unsigned short* __restrict__ P,
                                                         int rowstride, int coloff,
                                                         const float* __restrict__ bias,
                                                         const float* __restrict__ gamma,
                                                         const float* __restrict__ beta,
                                                         unsigned short* __restrict__ obf) {
  const int row = blockIdx.x;            // b*1024 + s
  const int b = row >> 10, s = row & 1023;
  const unsigned short* p = P + (size_t)row * rowstride + coloff;
  const int tid = threadIdx.x;
  const ushort4 pv = *(const ushort4*)(p + tid * 4);
  float4 v = {bf2f(pv.x), bf2f(pv.y), bf2f(pv.z), bf2f(pv.w)};
  const float4 bb = ((const float4*)bias)[tid];
  v.x += bb.x; v.y += bb.y; v.z += bb.z; v.w += bb.w;
  float sum = v.x + v.y + v.z + v.w;
  float s2 = v.x * v.x + v.y * v.y + v.z * v.z + v.w * v.w;
#pragma unroll
  for (int off = 32; off >= 1; off >>= 1) {
    sum += __shfl_xor(sum, off);
    s2 += __shfl_xor(s2, off);
  }
  __shared__ float red[2][4];
  const int wave = tid >> 6, lane = tid & 63;
  if (lane == 0) { red[0][wave] = sum; red[1][wave] = s2; }
  __syncthreads();
  sum = red[0][0] + red[0][1] + red[0][2] + red[0][3];
  s2 = red[1][0] + red[1][1] + red[1][2] + red[1][3];
  const float mu = sum * (1.0f / E_);
  const float var = s2 * (1.0f / E_) - mu * mu;
  const float r = rsqrtf(var + 1e-5f);
  const float4 g = ((const float4*)gamma)[tid];
  const float4 bt = ((const float4*)beta)[tid];
  const float o0 = fmaxf((v.x - mu) * r * g.x + bt.x, 0.0f);
  const float o1 = fmaxf((v.y - mu) * r * g.y + bt.y, 0.0f);
  const float o2 = fmaxf((v.z - mu) * r * g.z + bt.z, 0.0f);
  const float o3 = fmaxf((v.w - mu) * r * g.w + bt.w, 0.0f);
  const int h = tid >> 4;
  const int d = (tid & 15) << 2;
  const ushort4 ob = {f2bf(o0), f2bf(o1), f2bf(o2), f2bf(o3)};
  *(ushort4*)&obf[((size_t)(b * H_ + h) * S_ + s) * D_ + d] = ob;
}

// ---------------- fused scores + mask + softmax + head-mean (MFMA, no atomics) ------
__global__ __launch_bounds__(512, 2) void attn3_kernel(const unsigned short* __restrict__ Qbf,
                                                       const unsigned short* __restrict__ Kbf,
                                                       const unsigned char* __restrict__ msym,
                                                       float* __restrict__ out) {
  __shared__ __align__(16) float outAcc[16 * 1028];
  __shared__ __align__(16) float l_lds[8 * 16 * 16];
  __shared__ __align__(16) float linv_lds[16 * 16];
  unsigned char* smask = (unsigned char*)outAcc;
  const int tid = threadIdx.x;
  const int wave = tid >> 6, lane = tid & 63;
  const int ln15 = lane & 15, rg = lane >> 4;
  const int blk = blockIdx.x;
  const int b = blk & 3;
  const int q0 = (blk >> 2) << 4;

  {
    const int row = tid >> 5, c0 = (tid & 31) << 5;
    const uint4* src = (const uint4*)(msym + ((size_t)b * S_ + q0 + row) * S_ + c0);
    const uint4 m0 = src[0], m1 = src[1];
    *(uint4*)&smask[row * 1024 + c0] = m0;
    *(uint4*)&smask[row * 1024 + c0 + 16] = m1;
  }
  __syncthreads();
  unsigned int mrow[4] = {0u, 0u, 0u, 0u};
#pragma unroll
  for (int j = 0; j < 8; ++j) {
    const int col = (wave * 8 + j) * 16 + ln15;
#pragma unroll
    for (int r = 0; r < 4; ++r)
      mrow[r] |= (smask[(rg * 4 + r) * 1024 + col] ? 1u : 0u) << j;
  }

  const size_t bbase = (size_t)b * H_ * S_ * D_;
  const size_t qoff = (size_t)(q0 + ln15) * D_ + rg * 8;
  const size_t koff = (size_t)(wave * 128 + ln15) * D_ + rg * 8;

#pragma unroll 1
  for (int h = 0; h < 16; ++h) {
    const size_t hbase = bbase + (size_t)h * S_ * D_;
    const unsigned short* qp = Qbf + hbase + qoff;
    const short8 a0 = *(const short8*)qp;
    const short8 a1 = *(const short8*)(qp + 32);
    const unsigned short* kp = Kbf + hbase + koff;
    float la[4] = {0.0f, 0.0f, 0.0f, 0.0f};
#pragma unroll
    for (int j = 0; j < 8; ++j) {
      const unsigned short* kpj = kp + (size_t)j * (16 * D_);
      const short8 b0 = *(const short8*)kpj;
      const short8 b1 = *(const short8*)(kpj + 32);
      f32x4 c = {0.0f, 0.0f, 0.0f, 0.0f};
      c = __builtin_amdgcn_mfma_f32_16x16x32_bf16(a0, b0, c, 0, 0, 0);
      c = __builtin_amdgcn_mfma_f32_16x16x32_bf16(a1, b1, c, 0, 0, 0);
#pragma unroll
      for (int r = 0; r < 4; ++r) {
        const float s = fminf(c[r] * 0.125f, 80.0f);
        la[r] += ((mrow[r] >> j) & 1u) ? 0.0f : __expf(s);
      }
    }
#pragma unroll
    for (int r = 0; r < 4; ++r) {
      float lv = la[r];
      lv += __shfl_xor(lv, 1);
      lv += __shfl_xor(lv, 2);
      lv += __shfl_xor(lv, 4);
      lv += __shfl_xor(lv, 8);
      la[r] = lv;
    }
    if (ln15 == 0) {
      const float4 lw = {la[0], la[1], la[2], la[3]};
      *(float4*)&l_lds[(wave * 16 + h) * 16 + rg * 4] = lw;
    }
  }
  __syncthreads();
  if (tid < 256) {
    const int h = tid >> 4, q = tid & 15;
    float s = 0.0f;
#pragma unroll
    for (int w = 0; w < 8; ++w) s += l_lds[(w * 16 + h) * 16 + q];
    linv_lds[h * 16 + q] = 0.0625f / s;
  }
  __syncthreads();

  float o[8][4] = {};
#pragma unroll 1
  for (int h = 0; h < 16; ++h) {
    const size_t hbase = bbase + (size_t)h * S_ * D_;
    const unsigned short* qp = Qbf + hbase + qoff;
    const short8 a0 = *(const short8*)qp;
    const short8 a1 = *(const short8*)(qp + 32);
    const float4 li4 = *(const float4*)&linv_lds[h * 16 + rg * 4];
    const float li[4] = {li4.x, li4.y, li4.z, li4.w};
    const unsigned short* kp = Kbf + hbase + koff;
#pragma unroll
    for (int j = 0; j < 8; ++j) {
      const unsigned short* kpj = kp + (size_t)j * (16 * D_);
      const short8 b0 = *(const short8*)kpj;
      const short8 b1 = *(const short8*)(kpj + 32);
      f32x4 c = {0.0f, 0.0f, 0.0f, 0.0f};
      c = __builtin_amdgcn_mfma_f32_16x16x32_bf16(a0, b0, c, 0, 0, 0);
      c = __builtin_amdgcn_mfma_f32_16x16x32_bf16(a1, b1, c, 0, 0, 0);
#pragma unroll
      for (int r = 0; r < 4; ++r) {
        const float s = fminf(c[r] * 0.125f, 80.0f);
        const float e = ((mrow[r] >> j) & 1u) ? 0.0f : __expf(s);
        o[j][r] += e * li[r];
      }
    }
  }
#pragma unroll
  for (int j = 0; j < 8; ++j)
#pragma unroll
    for (int r = 0; r < 4; ++r)
      outAcc[(rg * 4 + r) * 1028 + (wave * 8 + j) * 16 + ln15] = o[j][r];
  __syncthreads();
  {
    const int row = tid >> 5, c0 = (tid & 31) << 5;
    float* dst = out + ((size_t)b * S_ + q0 + row) * S_ + c0;
    const float* srcA = &outAcc[row * 1028 + c0];
#pragma unroll
    for (int i = 0; i < 8; ++i)
      *(float4*)(dst + i * 4) = *(const float4*)(srcA + i * 4);
  }
}

extern "C" void kernel_launch(void* const* d_in, const int* in_sizes, int n_in,
                              void* d_out, int out_size, void* d_ws, size_t ws_size,
                              hipStream_t stream) {
  const float* x = (const float*)d_in[0];
  const int* mask = (const int*)d_in[1];
  const float* Wq = (const float*)d_in[2];
  const float* bq = (const float*)d_in[3];
  const float* Wk = (const float*)d_in[4];
  const float* bk = (const float*)d_in[5];
  const float* gq = (const float*)d_in[6];
  const float* bq_n = (const float*)d_in[7];
  const float* gk = (const float*)d_in[8];
  const float* bk_n = (const float*)d_in[9];
  float* out = (float*)d_out;

  char* ws = (char*)d_ws;
  const size_t MB = 1024 * 1024;

  if (ws_size >= 40 * MB) {
    // fused layout (40 MB): P2 bf16 [4096][2048] @0 (16), xbf @16 (8, Kbf aliases),
    // Wt @24 (4), Qbf @28 (8), msym @36 (4)
    unsigned short* P2 = (unsigned short*)ws;
    unsigned short* xbf = (unsigned short*)(ws + 16 * MB);
    unsigned short* Kbf = (unsigned short*)(ws + 16 * MB);   // alias: xbf dead after gemm
    unsigned short* Wt = (unsigned short*)(ws + 24 * MB);
    unsigned short* Qbf = (unsigned short*)(ws + 28 * MB);
    unsigned char* msym = (unsigned char*)(ws + 36 * MB);

    mask_sym_kernel<<<4096, 256, 0, stream>>>(mask, msym);
    cvt_x_kernel<<<2048, 256, 0, stream>>>(x, xbf);
    wt_kernel<<<2048, 256, 0, stream>>>(Wq, Wk, Wt);
    gemm_mfma_kernel<<<512, 256, 0, stream>>>(xbf, Wt, P2, 2048);
    ln_relu_bf_kernel<<<4096, 256, 0, stream>>>(P2, 2048, 0, bq, gq, bq_n, Qbf);
    ln_relu_bf_kernel<<<4096, 256, 0, stream>>>(P2, 2048, 1024, bk, gk, bk_n, Kbf);
    attn3_kernel<<<256, 512, 0, stream>>>(Qbf, Kbf, msym, out);
  } else {
    // split layout (32 MB): P bf16 [4096][1024] @0 (8), xbf @8 (8, Kbf aliases),
    // Wt @16 (4), Qbf @20 (8), msym @28 (4)
    unsigned short* P = (unsigned short*)ws;
    unsigned short* xbf = (unsigned short*)(ws + 8 * MB);
    unsigned short* Kbf = (unsigned short*)(ws + 8 * MB);    // alias: xbf dead after 2nd gemm
    unsigned short* Wt = (unsigned short*)(ws + 16 * MB);
    unsigned short* Qbf = (unsigned short*)(ws + 20 * MB);
    unsigned char* msym = (unsigned char*)(ws + 28 * MB);

    mask_sym_kernel<<<4096, 256, 0, stream>>>(mask, msym);
    cvt_x_kernel<<<2048, 256, 0, stream>>>(x, xbf);
    wt_kernel<<<2048, 256, 0, stream>>>(Wq, Wk, Wt);
    gemm_mfma_kernel<<<256, 256, 0, stream>>>(xbf, Wt, P, 1024);
    ln_relu_bf_kernel<<<4096, 256, 0, stream>>>(P, 1024, 0, bq, gq, bq_n, Qbf);
    gemm_mfma_kernel<<<256, 256, 0, stream>>>(xbf, Wt + (size_t)1024 * 1024, P, 1024);
    ln_relu_bf_kernel<<<4096, 256, 0, stream>>>(P, 1024, 0, bk, gk, bk_n, Kbf);
    attn3_kernel<<<256, 512, 0, stream>>>(Qbf, Kbf, msym, out);
  }
}